// Round 5
// baseline (144.891 us; speedup 1.0000x reference)
//
#include <hip/hip_runtime.h>
#include <hip/hip_cooperative_groups.h>

namespace cg = cooperative_groups;

#define BATCH 4
#define N_CH 3
#define NUM_CLASSES 20
#define IMG_H 512
#define IMG_W 512
#define MAX_BOXES 50
#define NSLOTS (BATCH * MAX_BOXES)
#define PARTS 16                    // work units per box slot
#define UNITS (NSLOTS * PARTS)      // 3200
#define BLOCK 256
#define GRID 1024                   // 4 blocks/CU x 256 CUs -> co-resident

// Single cooperative kernel:
//  phase 1: grid-stride over (slot, part) units; block computes the unit's
//           partial sum with aligned float4 loads, writes ws[unit].
//  grid.sync()
//  phase 2: block 0 reduces 3200 partials -> per-box err -> out[0].
__global__ __launch_bounds__(BLOCK, 4)
void fused_box_err(const float* __restrict__ y_fcn,
                   const float* __restrict__ im_data,
                   const int*   __restrict__ gt_boxes,
                   const int*   __restrict__ num_boxes,
                   float*       __restrict__ ws_part,
                   float*       __restrict__ out) {
    const int tid = (int)threadIdx.x;
    __shared__ float red[BLOCK / 64];
    const int plane = IMG_H * IMG_W;

    for (int unit = (int)blockIdx.x; unit < UNITS; unit += GRID) {
        const int slot = unit / PARTS;
        const int part = unit % PARTS;
        const int b    = slot / MAX_BOXES;
        const int box  = slot % MAX_BOXES;

        const int* g  = gt_boxes + slot * 5;
        const int x1 = g[0], y1 = g[1], x2 = g[2], y2 = g[3], cls = g[4];
        const int bh = y2 - y1;
        const int c0 = x1 & ~3;                    // 16B-aligned chunk start
        const int n4 = (x2 - c0 + 3) >> 2;         // float4 chunks per row

        const int nrows = (part < bh) ? ((bh - part + PARTS - 1) / PARTS) : 0;
        const int vmax  = (box < num_boxes[b]) ? nrows * n4 : 0;

        const float* im = im_data + (size_t)b * N_CH * plane;
        const float* yf = y_fcn + ((size_t)b * NUM_CLASSES + cls) * (size_t)(N_CH * plane);

        float s = 0.0f;
        for (int v = tid; v < vmax; v += BLOCK) {
            const int rl  = v / n4;
            const int ic  = v - rl * n4;
            const int row = y1 + part + rl * PARTS;
            const int cc  = c0 + (ic << 2);
            const int base = row * IMG_W + cc;     // float index, 16B aligned
            const float m0 = (cc + 0 >= x1 && cc + 0 < x2) ? 1.0f : 0.0f;
            const float m1 = (cc + 1 >= x1 && cc + 1 < x2) ? 1.0f : 0.0f;
            const float m2 = (cc + 2 >= x1 && cc + 2 < x2) ? 1.0f : 0.0f;
            const float m3 = (cc + 3 >= x1 && cc + 3 < x2) ? 1.0f : 0.0f;
            #pragma unroll
            for (int nn = 0; nn < N_CH; ++nn) {
                const float4 a = *(const float4*)(im + nn * plane + base);
                const float4 q = *(const float4*)(yf + nn * plane + base);
                float d;
                d = (a.x - q.x) * m0; s = fmaf(d, d, s);
                d = (a.y - q.y) * m1; s = fmaf(d, d, s);
                d = (a.z - q.z) * m2; s = fmaf(d, d, s);
                d = (a.w - q.w) * m3; s = fmaf(d, d, s);
            }
        }

        #pragma unroll
        for (int off = 32; off > 0; off >>= 1)
            s += __shfl_down(s, off, 64);

        if ((tid & 63) == 0) red[tid >> 6] = s;
        __syncthreads();
        if (tid == 0) {
            const float t4 = red[0] + red[1] + red[2] + red[3];
            // agent-scope store: visible across XCD L2s after grid sync
            __hip_atomic_store(&ws_part[unit], t4,
                               __ATOMIC_RELAXED, __HIP_MEMORY_SCOPE_AGENT);
        }
        __syncthreads();                           // red[] reused next unit
    }

    cg::this_grid().sync();

    if (blockIdx.x == 0) {
        float e = 0.0f;
        if (tid < NSLOTS) {
            const int b   = tid / MAX_BOXES;
            const int box = tid % MAX_BOXES;
            if (box < num_boxes[b]) {
                float sum = 0.0f;
                #pragma unroll
                for (int p = 0; p < PARTS; ++p)
                    sum += __hip_atomic_load(&ws_part[tid * PARTS + p],
                                             __ATOMIC_RELAXED, __HIP_MEMORY_SCOPE_AGENT);
                const int* g = gt_boxes + tid * 5;
                const int area = (g[2] - g[0]) * (g[3] - g[1]);
                e = sum / (float)(N_CH * max(area, 1));
            }
        }
        #pragma unroll
        for (int off = 32; off > 0; off >>= 1)
            e += __shfl_down(e, off, 64);

        if ((tid & 63) == 0) red[tid >> 6] = e;
        __syncthreads();
        if (tid == 0) {
            int nb = 0;
            #pragma unroll
            for (int bb = 0; bb < BATCH; ++bb) nb += num_boxes[bb];
            out[0] = (red[0] + red[1] + red[2] + red[3]) / (float)nb;
        }
    }
}

extern "C" void kernel_launch(void* const* d_in, const int* in_sizes, int n_in,
                              void* d_out, int out_size, void* d_ws, size_t ws_size,
                              hipStream_t stream) {
    const float* y_fcn     = (const float*)d_in[0];
    const float* im_data   = (const float*)d_in[1];
    // d_in[2] = im_info (unused)
    const int*   gt_boxes  = (const int*)d_in[3];
    const int*   num_boxes = (const int*)d_in[4];
    float* out     = (float*)d_out;
    float* ws_part = (float*)d_ws;             // UNITS floats

    void* args[] = { (void*)&y_fcn, (void*)&im_data, (void*)&gt_boxes,
                     (void*)&num_boxes, (void*)&ws_part, (void*)&out };
    hipLaunchCooperativeKernel((const void*)fused_box_err,
                               dim3(GRID), dim3(BLOCK), args, 0, stream);
}

// Round 7
// 90.522 us; speedup vs baseline: 1.6006x; 1.6006x over previous
//
#include <hip/hip_runtime.h>

#define BATCH 4
#define N_CH 3
#define NUM_CLASSES 20
#define IMG_H 512
#define IMG_W 512
#define MAX_BOXES 50
#define NSLOTS (BATCH * MAX_BOXES)   // 200
#define PARTS 16                     // blocks per box slot
#define UNITS (NSLOTS * PARTS)       // 3200 blocks
#define BLOCK 256
#define POISON32 0xAAAAAAAAu

// Single kernel, single graph node. Block (slot, part) computes its share of
// box `slot` with aligned float4 loads and writes a partial to ws. The LAST
// block to arrive per slot (exact election: counter == init+15, where init is
// 0 (fresh/self-cleaned) or 0xAAAAAAAA (harness poison)) folds the slot; the
// last slot-folder folds all 200 slot errors into out[0]. Counters self-clean
// to 0 after election, so every replay is deterministic.
__global__ __launch_bounds__(BLOCK)
void fused_box_err(const float* __restrict__ y_fcn,
                   const float* __restrict__ im_data,
                   const int*   __restrict__ gt_boxes,
                   const int*   __restrict__ num_boxes,
                   float*       __restrict__ ws,
                   float*       __restrict__ out) {
    float*    partials    = ws;                                    // UNITS floats
    float*    slot_err    = ws + UNITS;                            // NSLOTS floats
    unsigned* slot_done   = (unsigned*)(ws + UNITS + NSLOTS);      // NSLOTS u32
    unsigned* global_done = slot_done + NSLOTS;                    // 1 u32

    const int unit = (int)blockIdx.x;
    const int slot = unit / PARTS;
    const int part = unit & (PARTS - 1);
    const int b    = slot / MAX_BOXES;
    const int box  = slot % MAX_BOXES;
    const int tid  = (int)threadIdx.x;

    const int* g  = gt_boxes + slot * 5;
    const int x1 = g[0], y1 = g[1], x2 = g[2], y2 = g[3], cls = g[4];
    const int bh = y2 - y1;
    const int c0 = x1 & ~3;                    // 16B-aligned chunk start
    const int n4 = (x2 - c0 + 3) >> 2;         // float4 chunks per row

    const int nrows = (part < bh) ? ((bh - part + PARTS - 1) / PARTS) : 0;
    const int vmax  = (box < num_boxes[b]) ? nrows * n4 : 0;

    const int plane = IMG_H * IMG_W;
    const float* im = im_data + (size_t)b * N_CH * plane;
    const float* yf = y_fcn + ((size_t)b * NUM_CLASSES + cls) * (size_t)(N_CH * plane);

    float s = 0.0f;
    for (int v = tid; v < vmax; v += BLOCK) {
        const int rl  = v / n4;
        const int ic  = v - rl * n4;
        const int row = y1 + part + rl * PARTS;
        const int cc  = c0 + (ic << 2);
        const int base = row * IMG_W + cc;     // float index, 16B aligned
        const float m0 = (cc + 0 >= x1 && cc + 0 < x2) ? 1.0f : 0.0f;
        const float m1 = (cc + 1 >= x1 && cc + 1 < x2) ? 1.0f : 0.0f;
        const float m2 = (cc + 2 >= x1 && cc + 2 < x2) ? 1.0f : 0.0f;
        const float m3 = (cc + 3 >= x1 && cc + 3 < x2) ? 1.0f : 0.0f;
        #pragma unroll
        for (int nn = 0; nn < N_CH; ++nn) {
            const float4 a = *(const float4*)(im + nn * plane + base);
            const float4 q = *(const float4*)(yf + nn * plane + base);
            float d;
            d = (a.x - q.x) * m0; s = fmaf(d, d, s);
            d = (a.y - q.y) * m1; s = fmaf(d, d, s);
            d = (a.z - q.z) * m2; s = fmaf(d, d, s);
            d = (a.w - q.w) * m3; s = fmaf(d, d, s);
        }
    }

    #pragma unroll
    for (int off = 32; off > 0; off >>= 1)
        s += __shfl_down(s, off, 64);

    __shared__ float red[BLOCK / 64];
    __shared__ unsigned phs;
    if ((tid & 63) == 0) red[tid >> 6] = s;
    __syncthreads();

    if (tid == 0) {
        unsigned ph = 0;
        const float t4 = red[0] + red[1] + red[2] + red[3];
        __hip_atomic_store(&partials[unit], t4,
                           __ATOMIC_RELAXED, __HIP_MEMORY_SCOPE_AGENT);
        // release: partial store ordered before the counter tick
        const unsigned old = __hip_atomic_fetch_add(&slot_done[slot], 1u,
                               __ATOMIC_ACQ_REL, __HIP_MEMORY_SCOPE_AGENT);
        // exact last-arrival election for init 0 (fresh / self-cleaned)
        // or init 0xAAAAAAAA (harness poison)
        if (old == (PARTS - 1) || old == POISON32 + (PARTS - 1)) {
            float sum = 0.0f;
            #pragma unroll
            for (int p = 0; p < PARTS; ++p)
                sum += __hip_atomic_load(&partials[slot * PARTS + p],
                                         __ATOMIC_RELAXED, __HIP_MEMORY_SCOPE_AGENT);
            // self-clean for the next replay
            __hip_atomic_store(&slot_done[slot], 0u,
                               __ATOMIC_RELAXED, __HIP_MEMORY_SCOPE_AGENT);
            const int area = (x2 - x1) * (y2 - y1);
            const float e = sum / (float)(N_CH * max(area, 1)); // invalid slot: sum==0
            __hip_atomic_store(&slot_err[slot], e,
                               __ATOMIC_RELAXED, __HIP_MEMORY_SCOPE_AGENT);
            const unsigned old2 = __hip_atomic_fetch_add(global_done, 1u,
                                    __ATOMIC_ACQ_REL, __HIP_MEMORY_SCOPE_AGENT);
            if (old2 == (NSLOTS - 1) || old2 == POISON32 + (NSLOTS - 1)) {
                __hip_atomic_store(global_done, 0u,
                                   __ATOMIC_RELAXED, __HIP_MEMORY_SCOPE_AGENT);
                ph = 1;  // this block folds the 200 slot errors
            }
        }
        phs = ph;
    }
    __syncthreads();

    if (phs) {   // exactly one block per call, after ALL slots folded
        float e = 0.0f;
        if (tid < NSLOTS)
            e = __hip_atomic_load(&slot_err[tid],
                                  __ATOMIC_RELAXED, __HIP_MEMORY_SCOPE_AGENT);
        #pragma unroll
        for (int off = 32; off > 0; off >>= 1)
            e += __shfl_down(e, off, 64);
        if ((tid & 63) == 0) red[tid >> 6] = e;
        __syncthreads();
        if (tid == 0) {
            int nb = 0;
            #pragma unroll
            for (int bb = 0; bb < BATCH; ++bb) nb += num_boxes[bb];
            out[0] = (red[0] + red[1] + red[2] + red[3]) / (float)nb;
        }
    }
}

extern "C" void kernel_launch(void* const* d_in, const int* in_sizes, int n_in,
                              void* d_out, int out_size, void* d_ws, size_t ws_size,
                              hipStream_t stream) {
    const float* y_fcn     = (const float*)d_in[0];
    const float* im_data   = (const float*)d_in[1];
    // d_in[2] = im_info (unused)
    const int*   gt_boxes  = (const int*)d_in[3];
    const int*   num_boxes = (const int*)d_in[4];
    float* out = (float*)d_out;
    float* ws  = (float*)d_ws;   // UNITS+NSLOTS floats + (NSLOTS+1) u32

    fused_box_err<<<UNITS, BLOCK, 0, stream>>>(
        y_fcn, im_data, gt_boxes, num_boxes, ws, out);
}

// Round 8
// 18.414 us; speedup vs baseline: 7.8686x; 4.9159x over previous
//
#include <hip/hip_runtime.h>

#define BATCH 4
#define N_CH 3
#define NUM_CLASSES 20
#define IMG_H 512
#define IMG_W 512
#define MAX_BOXES 50
#define NSLOTS (BATCH * MAX_BOXES)   // 200
#define PARTS 16                     // blocks per box slot
#define UNITS (NSLOTS * PARTS)       // 3200 blocks
#define BLOCK 256
#define POISON32 0xAAAAAAAAu

// Single kernel, single graph node. Block (slot, part) computes its share of
// box `slot` with aligned float4 loads and writes a partial to ws. Election:
// last block per slot folds the slot; last slot-folder folds all slots into
// out[0]. ALL atomics are RELAXED agent-scope (cache-bypassing, no L2
// writeback/invalidate — the ACQ_REL version cost ~150us in R7!). Ordering is
// enforced with explicit s_waitcnt vmcnt(0): the partial store is ack'd at
// the coherence point before the counter RMW issues; RMWs serialize at the
// coherence point, so the last arrival sees all partials.
__global__ __launch_bounds__(BLOCK)
void fused_box_err(const float* __restrict__ y_fcn,
                   const float* __restrict__ im_data,
                   const int*   __restrict__ gt_boxes,
                   const int*   __restrict__ num_boxes,
                   float*       __restrict__ ws,
                   float*       __restrict__ out) {
    float*    partials    = ws;                                    // UNITS floats
    float*    slot_err    = ws + UNITS;                            // NSLOTS floats
    unsigned* slot_done   = (unsigned*)(ws + UNITS + NSLOTS);      // NSLOTS u32
    unsigned* global_done = slot_done + NSLOTS;                    // 1 u32

    const int unit = (int)blockIdx.x;
    const int slot = unit / PARTS;
    const int part = unit & (PARTS - 1);
    const int b    = slot / MAX_BOXES;
    const int box  = slot % MAX_BOXES;
    const int tid  = (int)threadIdx.x;

    const int* g  = gt_boxes + slot * 5;
    const int x1 = g[0], y1 = g[1], x2 = g[2], y2 = g[3], cls = g[4];
    const int bh = y2 - y1;
    const int c0 = x1 & ~3;                    // 16B-aligned chunk start
    const int n4 = (x2 - c0 + 3) >> 2;         // float4 chunks per row

    const int nrows = (part < bh) ? ((bh - part + PARTS - 1) / PARTS) : 0;
    const int vmax  = (box < num_boxes[b]) ? nrows * n4 : 0;

    const int plane = IMG_H * IMG_W;
    const float* im = im_data + (size_t)b * N_CH * plane;
    const float* yf = y_fcn + ((size_t)b * NUM_CLASSES + cls) * (size_t)(N_CH * plane);

    float s = 0.0f;
    for (int v = tid; v < vmax; v += BLOCK) {
        const int rl  = v / n4;
        const int ic  = v - rl * n4;
        const int row = y1 + part + rl * PARTS;
        const int cc  = c0 + (ic << 2);
        const int base = row * IMG_W + cc;     // float index, 16B aligned
        const float m0 = (cc + 0 >= x1 && cc + 0 < x2) ? 1.0f : 0.0f;
        const float m1 = (cc + 1 >= x1 && cc + 1 < x2) ? 1.0f : 0.0f;
        const float m2 = (cc + 2 >= x1 && cc + 2 < x2) ? 1.0f : 0.0f;
        const float m3 = (cc + 3 >= x1 && cc + 3 < x2) ? 1.0f : 0.0f;
        #pragma unroll
        for (int nn = 0; nn < N_CH; ++nn) {
            const float4 a = *(const float4*)(im + nn * plane + base);
            const float4 q = *(const float4*)(yf + nn * plane + base);
            float d;
            d = (a.x - q.x) * m0; s = fmaf(d, d, s);
            d = (a.y - q.y) * m1; s = fmaf(d, d, s);
            d = (a.z - q.z) * m2; s = fmaf(d, d, s);
            d = (a.w - q.w) * m3; s = fmaf(d, d, s);
        }
    }

    #pragma unroll
    for (int off = 32; off > 0; off >>= 1)
        s += __shfl_down(s, off, 64);

    __shared__ float red[BLOCK / 64];
    __shared__ unsigned phs;
    if ((tid & 63) == 0) red[tid >> 6] = s;
    __syncthreads();

    if (tid == 0) {
        unsigned ph = 0;
        const float t4 = red[0] + red[1] + red[2] + red[3];
        __hip_atomic_store(&partials[unit], t4,
                           __ATOMIC_RELAXED, __HIP_MEMORY_SCOPE_AGENT);
        // hand-rolled release: wait until the partial store is ack'd at the
        // coherence point, WITHOUT the compiler's L2 writeback/invalidate
        asm volatile("s_waitcnt vmcnt(0)" ::: "memory");
        const unsigned old = __hip_atomic_fetch_add(&slot_done[slot], 1u,
                               __ATOMIC_RELAXED, __HIP_MEMORY_SCOPE_AGENT);
        // exact last-arrival election for init 0 (fresh / self-cleaned)
        // or init 0xAAAAAAAA (harness poison)
        if (old == (PARTS - 1) || old == POISON32 + (PARTS - 1)) {
            float sum = 0.0f;
            #pragma unroll
            for (int p = 0; p < PARTS; ++p)
                sum += __hip_atomic_load(&partials[slot * PARTS + p],
                                         __ATOMIC_RELAXED, __HIP_MEMORY_SCOPE_AGENT);
            // self-clean for the next replay
            __hip_atomic_store(&slot_done[slot], 0u,
                               __ATOMIC_RELAXED, __HIP_MEMORY_SCOPE_AGENT);
            const int area = (x2 - x1) * (y2 - y1);
            const float e = sum / (float)(N_CH * max(area, 1)); // invalid slot: sum==0
            __hip_atomic_store(&slot_err[slot], e,
                               __ATOMIC_RELAXED, __HIP_MEMORY_SCOPE_AGENT);
            asm volatile("s_waitcnt vmcnt(0)" ::: "memory");
            const unsigned old2 = __hip_atomic_fetch_add(global_done, 1u,
                                    __ATOMIC_RELAXED, __HIP_MEMORY_SCOPE_AGENT);
            if (old2 == (NSLOTS - 1) || old2 == POISON32 + (NSLOTS - 1)) {
                __hip_atomic_store(global_done, 0u,
                                   __ATOMIC_RELAXED, __HIP_MEMORY_SCOPE_AGENT);
                ph = 1;  // this block folds the 200 slot errors
            }
        }
        phs = ph;
    }
    __syncthreads();

    if (phs) {   // exactly one block per call, after ALL slots folded
        float e = 0.0f;
        if (tid < NSLOTS)
            e = __hip_atomic_load(&slot_err[tid],
                                  __ATOMIC_RELAXED, __HIP_MEMORY_SCOPE_AGENT);
        #pragma unroll
        for (int off = 32; off > 0; off >>= 1)
            e += __shfl_down(e, off, 64);
        if ((tid & 63) == 0) red[tid >> 6] = e;
        __syncthreads();
        if (tid == 0) {
            int nb = 0;
            #pragma unroll
            for (int bb = 0; bb < BATCH; ++bb) nb += num_boxes[bb];
            out[0] = (red[0] + red[1] + red[2] + red[3]) / (float)nb;
        }
    }
}

extern "C" void kernel_launch(void* const* d_in, const int* in_sizes, int n_in,
                              void* d_out, int out_size, void* d_ws, size_t ws_size,
                              hipStream_t stream) {
    const float* y_fcn     = (const float*)d_in[0];
    const float* im_data   = (const float*)d_in[1];
    // d_in[2] = im_info (unused)
    const int*   gt_boxes  = (const int*)d_in[3];
    const int*   num_boxes = (const int*)d_in[4];
    float* out = (float*)d_out;
    float* ws  = (float*)d_ws;   // UNITS+NSLOTS floats + (NSLOTS+1) u32

    fused_box_err<<<UNITS, BLOCK, 0, stream>>>(
        y_fcn, im_data, gt_boxes, num_boxes, ws, out);
}

// Round 9
// 15.189 us; speedup vs baseline: 9.5394x; 1.2123x over previous
//
#include <hip/hip_runtime.h>

#define BATCH 4
#define N_CH 3
#define NUM_CLASSES 20
#define IMG_H 512
#define IMG_W 512
#define MAX_BOXES 50
#define NSLOTS (BATCH * MAX_BOXES)
#define PARTS 16                    // blocks per box slot
#define BLOCK 256
#define TOTAL_BLOCKS (NSLOTS * PARTS)   // 3200

// Block (slot, part) sums its share of box `slot` with aligned float4 loads
// and writes the FULLY NORMALIZED contribution
//   ws[blockIdx.x] = partial_sum / (N_CH * area * sum(num_boxes))
// (0 for invalid slots). Every block overwrites its ws element -> no
// zero-init, no atomics, poison-safe.
__global__ __launch_bounds__(BLOCK)
void box_err_kernel(const float* __restrict__ y_fcn,
                    const float* __restrict__ im_data,
                    const int*   __restrict__ gt_boxes,
                    const int*   __restrict__ num_boxes,
                    float*       __restrict__ ws_part) {
    const int slot = blockIdx.x / PARTS;
    const int part = blockIdx.x % PARTS;
    const int b    = slot / MAX_BOXES;
    const int box  = slot % MAX_BOXES;
    const int tid  = (int)threadIdx.x;

    const int* g  = gt_boxes + slot * 5;
    const int x1 = g[0], y1 = g[1], x2 = g[2], y2 = g[3], cls = g[4];
    const int bh = y2 - y1;
    const int c0 = x1 & ~3;                    // 16B-aligned chunk start
    const int n4 = (x2 - c0 + 3) >> 2;         // float4 chunks per row

    const int nrows = (part < bh) ? ((bh - part + PARTS - 1) / PARTS) : 0;
    const int vmax  = (box < num_boxes[b]) ? nrows * n4 : 0;

    const int plane = IMG_H * IMG_W;
    const float* im = im_data + (size_t)b * N_CH * plane;
    const float* yf = y_fcn + ((size_t)b * NUM_CLASSES + cls) * (size_t)(N_CH * plane);

    float s = 0.0f;
    for (int v = tid; v < vmax; v += BLOCK) {
        const int rl  = v / n4;
        const int ic  = v - rl * n4;
        const int row = y1 + part + rl * PARTS;
        const int cc  = c0 + (ic << 2);
        const int base = row * IMG_W + cc;     // float index, 16B aligned
        const float m0 = (cc + 0 >= x1 && cc + 0 < x2) ? 1.0f : 0.0f;
        const float m1 = (cc + 1 >= x1 && cc + 1 < x2) ? 1.0f : 0.0f;
        const float m2 = (cc + 2 >= x1 && cc + 2 < x2) ? 1.0f : 0.0f;
        const float m3 = (cc + 3 >= x1 && cc + 3 < x2) ? 1.0f : 0.0f;
        #pragma unroll
        for (int nn = 0; nn < N_CH; ++nn) {
            const float4 a = *(const float4*)(im + nn * plane + base);
            const float4 q = *(const float4*)(yf + nn * plane + base);
            float d;
            d = (a.x - q.x) * m0; s = fmaf(d, d, s);
            d = (a.y - q.y) * m1; s = fmaf(d, d, s);
            d = (a.z - q.z) * m2; s = fmaf(d, d, s);
            d = (a.w - q.w) * m3; s = fmaf(d, d, s);
        }
    }

    #pragma unroll
    for (int off = 32; off > 0; off >>= 1)
        s += __shfl_down(s, off, 64);

    __shared__ float red[BLOCK / 64];
    if ((tid & 63) == 0) red[tid >> 6] = s;
    __syncthreads();
    if (tid == 0) {
        int nb = 0;
        #pragma unroll
        for (int bb = 0; bb < BATCH; ++bb) nb += num_boxes[bb];   // uniform s_loads
        const int area = (x2 - x1) * (y2 - y1);
        const float denom = (float)(N_CH * max(area, 1)) * (float)nb;
        ws_part[blockIdx.x] = (red[0] + red[1] + red[2] + red[3]) / denom;
    }
}

// One block: pure sum of the 3200 normalized contributions -> out[0].
// No gt_boxes / num_boxes dependency in the critical path.
__global__ __launch_bounds__(BLOCK)
void finalize_kernel(const float* __restrict__ ws_part,
                     float*       __restrict__ out) {
    const int t = (int)threadIdx.x;
    float e = 0.0f;
    #pragma unroll
    for (int k = t; k < TOTAL_BLOCKS; k += BLOCK)
        e += ws_part[k];                        // 13 coalesced loads, all in flight

    #pragma unroll
    for (int off = 32; off > 0; off >>= 1)
        e += __shfl_down(e, off, 64);

    __shared__ float red[BLOCK / 64];
    if ((t & 63) == 0) red[t >> 6] = e;
    __syncthreads();
    if (t == 0)
        out[0] = red[0] + red[1] + red[2] + red[3];
}

extern "C" void kernel_launch(void* const* d_in, const int* in_sizes, int n_in,
                              void* d_out, int out_size, void* d_ws, size_t ws_size,
                              hipStream_t stream) {
    const float* y_fcn     = (const float*)d_in[0];
    const float* im_data   = (const float*)d_in[1];
    // d_in[2] = im_info (unused)
    const int*   gt_boxes  = (const int*)d_in[3];
    const int*   num_boxes = (const int*)d_in[4];
    float* out     = (float*)d_out;
    float* ws_part = (float*)d_ws;         // TOTAL_BLOCKS floats

    box_err_kernel<<<TOTAL_BLOCKS, BLOCK, 0, stream>>>(
        y_fcn, im_data, gt_boxes, num_boxes, ws_part);

    finalize_kernel<<<1, BLOCK, 0, stream>>>(ws_part, out);
}